// Round 1
// 216.306 us; speedup vs baseline: 1.0836x; 1.0836x over previous
//
#include <hip/hip_runtime.h>

#define SEQ 128
#define BATCH 512
#define IN_DIM 128
#define HID 128

typedef float vf2 __attribute__((ext_vector_type(2)));

__device__ __forceinline__ float rcp_f(float x) { return __builtin_amdgcn_rcpf(x); }
__device__ __forceinline__ float tanh_f(float x) { return 1.0f - 2.0f * rcp_f(__expf(2.0f * x) + 1.0f); }

template <int CTRL>
__device__ __forceinline__ float dpp_add(float s) {
  return s + __int_as_float(__builtin_amdgcn_mov_dpp(__float_as_int(s), CTRL, 0xF, 0xF, true));
}

__device__ __forceinline__ float rdlane(float v, int src) {
  return __int_as_float(__builtin_amdgcn_readlane(__float_as_int(v), src));
}

// From register x whose 16-lane quarters hold [q0,q1,q2,q3], give EVERY lane
// (q0,q1,q2,q3) at its own p = lane&15.  Pure VALU cross-lane (no LDS memory).
__device__ __forceinline__ void quarter_bcast(float x, float& r0, float& r1, float& r2, float& r3) {
  unsigned xu = __float_as_uint(x);
  auto pr = __builtin_amdgcn_permlane32_swap(xu, xu, false, false); // pr[0]=[q0,q1,q0,q1] pr[1]=[q2,q3,q2,q3]
#if __has_builtin(__builtin_amdgcn_permlane16_swap)
  auto lo = __builtin_amdgcn_permlane16_swap(pr[0], pr[0], false, false); // [q0 x4],[q1 x4]
  auto hi = __builtin_amdgcn_permlane16_swap(pr[1], pr[1], false, false); // [q2 x4],[q3 x4]
  r0 = __uint_as_float(lo[0]); r1 = __uint_as_float(lo[1]);
  r2 = __uint_as_float(hi[0]); r3 = __uint_as_float(hi[1]);
#else
  // ds_swizzle xor-16 fallback (BitMode: xor=16, and=31)
  unsigned s0 = (unsigned)__builtin_amdgcn_ds_swizzle((int)pr[0], 0x401F);
  unsigned s1 = (unsigned)__builtin_amdgcn_ds_swizzle((int)pr[1], 0x401F);
  const bool qo = (threadIdx.x >> 4) & 1;
  r0 = __uint_as_float(qo ? s0 : pr[0]);
  r1 = __uint_as_float(qo ? pr[0] : s0);
  r2 = __uint_as_float(qo ? s1 : pr[1]);
  r3 = __uint_as_float(qo ? pr[1] : s1);
#endif
}

// ONE WAVE per batch element, ZERO LDS in the loop.
// Lane = (G = lane>>4, p = lane&15).  G is gate id (f,i,g,o) AND wire-pair id
// {2G,2G+1}.  Lane owns dims 8p..8p+7 of x, h, c.  All exchanges are DPP /
// readlane / permlane-swap (VALU pipe) -- no lgkmcnt waits on the chain.
__global__ __launch_bounds__(64) void qlstm_kernel(
    const float* __restrict__ X, const float* __restrict__ Wq, const float* __restrict__ bq,
    const float* __restrict__ pf, const float* __restrict__ pi_, const float* __restrict__ pg,
    const float* __restrict__ po, const float* __restrict__ Wf, const float* __restrict__ bf,
    const float* __restrict__ Wi, const float* __restrict__ bi, const float* __restrict__ Wg,
    const float* __restrict__ bg, const float* __restrict__ Wo, const float* __restrict__ bo,
    float* __restrict__ out)
{
  const int lane = threadIdx.x;
  const int G = lane >> 4;
  const int p = lane & 15;
  const int b = blockIdx.x;

  const float* gW = (G == 0) ? Wf : (G == 1) ? Wi : (G == 2) ? Wg : Wo;
  const float* gB = (G == 0) ? bf : (G == 1) ? bi : (G == 2) ? bg : bo;
  const float* gP = (G == 0) ? pf : (G == 1) ? pi_ : (G == 2) ? pg : po;

  // ---- one-time register preloads ----
  // q_in dot weights: wires 2G (E) / 2G+1 (O), x-part and h-part, dims 8p..8p+7
  vf2 wxE[4], wxO[4], whE[4], whO[4];
  {
    const vf2* pa = (const vf2*)(Wq + (2 * G) * 256 + 8 * p);
    const vf2* pbh = (const vf2*)(Wq + (2 * G) * 256 + 128 + 8 * p);
    const vf2* pc = (const vf2*)(Wq + (2 * G + 1) * 256 + 8 * p);
    const vf2* pdh = (const vf2*)(Wq + (2 * G + 1) * 256 + 128 + 8 * p);
#pragma unroll
    for (int j = 0; j < 4; ++j) { wxE[j] = pa[j]; whE[j] = pbh[j]; wxO[j] = pc[j]; whO[j] = pdh[j]; }
  }
  const float bqv = bq[2 * G + (p >> 3)];

  // gate-GEMM weights: gate G, h-dims 8p..8p+7
  vf2 wg2[8][4];
#pragma unroll
  for (int w = 0; w < 8; ++w)
#pragma unroll
    for (int j = 0; j < 4; ++j) {
      wg2[w][j].x = gW[(8 * p + 2 * j) * 8 + w];
      wg2[w][j].y = gW[(8 * p + 2 * j + 1) * 8 + w];
    }
  vf2 bias2[4];
#pragma unroll
  for (int j = 0; j < 4; ++j) {
    bias2[j].x = gB[8 * p + 2 * j];
    bias2[j].y = gB[8 * p + 2 * j + 1];
  }
  // TM constants for THIS lane's gate
  vf2 cbsb[8];
  float C1[8], S1[8];
#pragma unroll
  for (int w = 0; w < 8; ++w) {
    float th0 = gP[w], th1 = gP[8 + w];
    cbsb[w].x = cosf(th0); cbsb[w].y = sinf(th0);
    C1[w] = cosf(th1); S1[w] = sinf(th1);
  }
  const float amul = (G == 2) ? 2.0f : 1.0f;   // tanh = 2*sigmoid(2x)-1
  const float oadd = (G == 2) ? -1.0f : 0.0f;

  // state (replicated across the 4 quarters -- consistent by construction)
  float c8[8], h8[8];
#pragma unroll
  for (int k = 0; k < 8; ++k) { c8[k] = 0.0f; h8[k] = 0.0f; }

  const float* xp = X + (size_t)b * IN_DIM + 8 * p;
  float* outp = out + (size_t)b * HID + 8 * p;

  float4 xa, xb, xa2 = {0, 0, 0, 0}, xb2 = {0, 0, 0, 0};
  xa = *(const float4*)(xp);
  xb = *(const float4*)(xp + 4);

#define QSTEP(XA, XB, XAN, XBN, T, PREF)                                         \
  {                                                                              \
    if (PREF) {                                                                  \
      const float* xn_ = xp + (size_t)((T) + 1) * (BATCH * IN_DIM);              \
      XAN = *(const float4*)(xn_);                                               \
      XBN = *(const float4*)(xn_ + 4);                                           \
    }                                                                            \
    vf2 x0_ = {XA.x, XA.y}, x1_ = {XA.z, XA.w};                                  \
    vf2 x2_ = {XB.x, XB.y}, x3_ = {XB.z, XB.w};                                  \
    vf2 h0_ = {h8[0], h8[1]}, h1_ = {h8[2], h8[3]};                              \
    vf2 h2_ = {h8[4], h8[5]}, h3_ = {h8[6], h8[7]};                              \
    vf2 pe_ = wxE[0] * x0_ + wxE[1] * x1_ + wxE[2] * x2_ + wxE[3] * x3_          \
            + whE[0] * h0_ + whE[1] * h1_ + whE[2] * h2_ + whE[3] * h3_;         \
    vf2 po_ = wxO[0] * x0_ + wxO[1] * x1_ + wxO[2] * x2_ + wxO[3] * x3_          \
            + whO[0] * h0_ + whO[1] * h1_ + whO[2] * h2_ + whO[3] * h3_;         \
    float sE_ = pe_.x + pe_.y, sO_ = po_.x + po_.y;                              \
    sE_ = dpp_add<0xB1>(sE_);  sO_ = dpp_add<0xB1>(sO_);                         \
    sE_ = dpp_add<0x4E>(sE_);  sO_ = dpp_add<0x4E>(sO_);                         \
    sE_ = dpp_add<0x141>(sE_); sO_ = dpp_add<0x141>(sO_);                        \
    sE_ = dpp_add<0x140>(sE_); sO_ = dpp_add<0x140>(sO_);                        \
    float z_ = ((p & 8) ? sO_ : sE_) + bqv;                                      \
    float sz_, cz_;                                                              \
    __sincosf(z_, &sz_, &cz_);                                                   \
    float cqs[8], sqs[8];                                                        \
    _Pragma("unroll")                                                            \
    for (int w = 0; w < 8; ++w) {                                                \
      const int src = 16 * (w >> 1) + 8 * (w & 1);                               \
      cqs[w] = rdlane(cz_, src);                                                 \
      sqs[w] = rdlane(sz_, src);                                                 \
    }                                                                            \
    vf2 acc0 = bias2[0], acc1 = bias2[1], acc2 = bias2[2], acc3 = bias2[3];      \
    float u_, d_, P_, R_;                                                        \
    {                                                                            \
      vf2 KA0 = cbsb[0] * cqs[0];                                                \
      u_ = C1[0]; d_ = C1[0] * KA0.x;                                            \
      P_ = -S1[0] * KA0.y; R_ = -S1[0] * sqs[0];                                 \
    }                                                                            \
    _Pragma("unroll")                                                            \
    for (int w = 1; w < 8; ++w) {                                                \
      vf2 KA = cbsb[w] * cqs[w];                                                 \
      float K_ = KA.x, A2_ = KA.y, B2_ = sqs[w];                                 \
      float Md = fmaf(A2_, P_, d_);                                              \
      float MP = fmaf(A2_, d_, P_);                                              \
      float Mu = fmaf(K_, u_, -(B2_ * R_));                                      \
      float MR = fmaf(B2_, u_, K_ * R_);                                         \
      acc0 += Md * wg2[w - 1][0]; acc1 += Md * wg2[w - 1][1];                    \
      acc2 += Md * wg2[w - 1][2]; acc3 += Md * wg2[w - 1][3];                    \
      u_ = C1[w] * Md; d_ = C1[w] * Mu;                                          \
      P_ = -S1[w] * MP; R_ = -S1[w] * MR;                                        \
    }                                                                            \
    float ev7_ = d_ + P_;                                                        \
    acc0 += ev7_ * wg2[7][0]; acc1 += ev7_ * wg2[7][1];                          \
    acc2 += ev7_ * wg2[7][2]; acc3 += ev7_ * wg2[7][3];                          \
    float av_[8] = {acc0.x, acc0.y, acc1.x, acc1.y, acc2.x, acc2.y, acc3.x, acc3.y}; \
    _Pragma("unroll")                                                            \
    for (int k = 0; k < 8; ++k) {                                                \
      float e_ = __expf(-amul * av_[k]);                                         \
      float ok_ = fmaf(rcp_f(1.0f + e_), amul, oadd);                            \
      float Fv_, Iv_, Gg_, Ov_;                                                  \
      quarter_bcast(ok_, Fv_, Iv_, Gg_, Ov_);                                    \
      float cv_ = fmaf(Fv_, c8[k], Iv_ * Gg_);                                   \
      c8[k] = cv_;                                                               \
      h8[k] = Ov_ * tanh_f(cv_);                                                 \
    }                                                                            \
    if (G == 0) {                                                                \
      float* op_ = outp + (size_t)(T) * (BATCH * HID);                           \
      float4 s0_, s1_;                                                           \
      s0_.x = h8[0]; s0_.y = h8[1]; s0_.z = h8[2]; s0_.w = h8[3];                \
      s1_.x = h8[4]; s1_.y = h8[5]; s1_.z = h8[6]; s1_.w = h8[7];                \
      *(float4*)(op_) = s0_;                                                     \
      *(float4*)(op_ + 4) = s1_;                                                 \
    }                                                                            \
  }

#pragma unroll 1
  for (int tt = 0; tt < SEQ; tt += 2) {
    QSTEP(xa, xb, xa2, xb2, tt, true);
    QSTEP(xa2, xb2, xa, xb, tt + 1, (tt + 2 < SEQ));
  }
#undef QSTEP

  // hx, cx
  if (G == 0) {
    size_t base = (size_t)SEQ * BATCH * HID;
    float* hp = out + base + (size_t)b * HID + 8 * p;
    float* cp = out + base + (size_t)BATCH * HID + (size_t)b * HID + 8 * p;
    float4 v0, v1;
    v0.x = h8[0]; v0.y = h8[1]; v0.z = h8[2]; v0.w = h8[3];
    v1.x = h8[4]; v1.y = h8[5]; v1.z = h8[6]; v1.w = h8[7];
    *(float4*)(hp) = v0; *(float4*)(hp + 4) = v1;
    v0.x = c8[0]; v0.y = c8[1]; v0.z = c8[2]; v0.w = c8[3];
    v1.x = c8[4]; v1.y = c8[5]; v1.z = c8[6]; v1.w = c8[7];
    *(float4*)(cp) = v0; *(float4*)(cp + 4) = v1;
  }
}

extern "C" void kernel_launch(void* const* d_in, const int* in_sizes, int n_in,
                              void* d_out, int out_size, void* d_ws, size_t ws_size,
                              hipStream_t stream) {
  (void)in_sizes; (void)n_in; (void)out_size; (void)d_ws; (void)ws_size;
  const float* X   = (const float*)d_in[0];
  const float* Wq  = (const float*)d_in[1];
  const float* bq  = (const float*)d_in[2];
  const float* pf  = (const float*)d_in[3];
  const float* pi_ = (const float*)d_in[4];
  const float* pg  = (const float*)d_in[5];
  const float* po  = (const float*)d_in[6];
  const float* Wf  = (const float*)d_in[7];
  const float* bf  = (const float*)d_in[8];
  const float* Wi  = (const float*)d_in[9];
  const float* bi  = (const float*)d_in[10];
  const float* Wg  = (const float*)d_in[11];
  const float* bg  = (const float*)d_in[12];
  const float* Wo  = (const float*)d_in[13];
  const float* bo  = (const float*)d_in[14];
  float* out = (float*)d_out;

  qlstm_kernel<<<BATCH, 64, 0, stream>>>(X, Wq, bq, pf, pi_, pg, po,
                                         Wf, bf, Wi, bi, Wg, bg, Wo, bo, out);
}